// Round 3
// baseline (173.718 us; speedup 1.0000x reference)
//
#include <hip/hip_runtime.h>

#define NG 76
#define NPOS (NG * NG)            // 5776
#define NC 85                     // 5 + 80
#define NA 3
#define PPB 76                    // positions per block = one grid row
#define TPP (NPOS / PPB)          // 76 tiles per plane
#define ROWV (PPB / 4)            // 19 float4 per channel row
#define NV (NC * ROWV)            // 1615 float4 per tile
#define NITER 7                   // ceil(1615 / 256)
#define STRIDE_F 8.0f             // 608 / 76

typedef float floatx4 __attribute__((ext_vector_type(4)));   // clang-native vec

// exp(w) * scaled_anchor * stride == exp(w) * ANCHOR
__constant__ float c_aw[NA] = {10.0f, 16.0f, 33.0f};
__constant__ float c_ah[NA] = {13.0f, 30.0f, 23.0f};

__device__ __forceinline__ float fsig(float x) {
    return __builtin_amdgcn_rcpf(1.0f + __expf(-x));
}

__global__ __launch_bounds__(256) void det_kernel(const float* __restrict__ in,
                                                  float* __restrict__ out) {
    // LDS tile in OUTPUT order: idx = p*NC + c  (p = position within row, 0..75)
    __shared__ float lds[PPB * NC];

    const int bid   = blockIdx.x;
    const int plane = bid / TPP;            // b*NA + a
    const int tile  = bid - plane * TPP;    // grid row  (== gy for all elems)
    const int a     = plane % NA;
    const int t     = threadIdx.x;

    const float* ip = in + (size_t)plane * (NC * NPOS) + tile * PPB;

    // ---- phase 1a: batch-issue ALL global loads into registers (max MLP) ----
    floatx4 r[NITER];
    #pragma unroll
    for (int i = 0; i < NITER; ++i) {
        const int v = t + 256 * i;
        if (v < NV) {
            const int c  = v / ROWV;        // channel 0..84
            const int pq = v - c * ROWV;    // float4 index within row 0..18
            r[i] = *reinterpret_cast<const floatx4*>(ip + c * NPOS + pq * 4);
        }
    }

    // ---- phase 1b: scatter-transpose into LDS (output order) ----
    #pragma unroll
    for (int i = 0; i < NITER; ++i) {
        const int v = t + 256 * i;
        if (v < NV) {
            const int c  = v / ROWV;
            const int pq = v - c * ROWV;
            const int p  = pq * 4;
            lds[(p + 0) * NC + c] = r[i].x;
            lds[(p + 1) * NC + c] = r[i].y;
            lds[(p + 2) * NC + c] = r[i].z;
            lds[(p + 3) * NC + c] = r[i].w;
        }
    }
    __syncthreads();

    // ---- phase 2: ds_read_b128 + transform + contiguous nontemporal stores ----
    float* ob = out + (size_t)plane * (NPOS * NC) + (size_t)tile * (PPB * NC);
    const float aw = c_aw[a];
    const float ah = c_ah[a];
    const float gy = (float)tile;

    #pragma unroll
    for (int i = 0; i < NITER; ++i) {
        const int v = t + 256 * i;
        if (v < NV) {
            const int e0 = 4 * v;
            const floatx4 f = *reinterpret_cast<const floatx4*>(&lds[e0]);
            float xin[4] = {f.x, f.y, f.z, f.w};
            float res[4];
            int p = e0 / NC;
            int c = e0 - p * NC;
            #pragma unroll
            for (int k = 0; k < 4; ++k) {
                const float x = xin[k];
                float rr;
                if (c >= 4) {                    // conf + 80 classes
                    rr = fsig(x);
                } else if (c == 2) {             // box w
                    rr = __expf(x) * aw;
                } else if (c == 3) {             // box h
                    rr = __expf(x) * ah;
                } else {                         // box x / y
                    const float g = (c == 0) ? (float)p : gy;
                    rr = (fsig(x) + g) * STRIDE_F;
                }
                res[k] = rr;
                if (++c == NC) { c = 0; ++p; }
            }
            floatx4 o;
            o.x = res[0]; o.y = res[1]; o.z = res[2]; o.w = res[3];
            __builtin_nontemporal_store(o, reinterpret_cast<floatx4*>(ob + e0));
        }
    }
}

extern "C" void kernel_launch(void* const* d_in, const int* in_sizes, int n_in,
                              void* d_out, int out_size, void* d_ws, size_t ws_size,
                              hipStream_t stream) {
    const float* x = (const float*)d_in[0];
    float* out     = (float*)d_out;
    const int nB     = in_sizes[0] / (NA * NC * NPOS);   // 16
    const int blocks = nB * NA * TPP;                    // 16*3*76 = 3648
    det_kernel<<<blocks, 256, 0, stream>>>(x, out);
}

// Round 4
// 166.440 us; speedup vs baseline: 1.0437x; 1.0437x over previous
//
#include <hip/hip_runtime.h>

#define NG 76
#define NPOS (NG * NG)            // 5776
#define NC 85                     // 5 + 80
#define NA 3
#define PPB 76                    // positions per block = one grid row
#define TPP (NPOS / PPB)          // 76 tiles per plane
#define ROWV (PPB / 4)            // 19 float4 per channel row
#define NV (NC * ROWV)            // 1615 float4 per tile
#define BLK 512
#define NITER 4                   // ceil(1615 / 512)
#define STRIDE_F 8.0f             // 608 / 76

typedef float floatx4 __attribute__((ext_vector_type(4)));

// exp(w) * scaled_anchor * stride == exp(w) * ANCHOR
__constant__ float c_aw[NA] = {10.0f, 16.0f, 33.0f};
__constant__ float c_ah[NA] = {13.0f, 30.0f, 23.0f};

__device__ __forceinline__ float fsig(float x) {
    return __builtin_amdgcn_rcpf(1.0f + __expf(-x));
}

__global__ __launch_bounds__(BLK) void det_kernel(const float* __restrict__ in,
                                                  float* __restrict__ out) {
    // LDS tile in OUTPUT order: idx = p*NC + c  (p = position within row, 0..75)
    __shared__ float lds[PPB * NC];

    const int bid   = blockIdx.x;
    const int plane = bid / TPP;            // b*NA + a
    const int tile  = bid - plane * TPP;    // grid row == gy
    const int a     = plane % NA;
    const int t     = threadIdx.x;

    const float* ip = in + (size_t)plane * (NC * NPOS) + tile * PPB;

    // ---- phase 1a: batch-issue all global loads into registers (max MLP) ----
    floatx4 r[NITER];
    #pragma unroll
    for (int i = 0; i < NITER; ++i) {
        const int v = t + BLK * i;
        if (v < NV) {
            const int c  = v / ROWV;        // channel 0..84
            const int pq = v - c * ROWV;    // float4 index within row 0..18
            r[i] = *reinterpret_cast<const floatx4*>(ip + c * NPOS + pq * 4);
        }
    }

    // ---- phase 1b: scatter-transpose into LDS (output order) ----
    #pragma unroll
    for (int i = 0; i < NITER; ++i) {
        const int v = t + BLK * i;
        if (v < NV) {
            const int c  = v / ROWV;
            const int pq = v - c * ROWV;
            const int p  = pq * 4;
            lds[(p + 0) * NC + c] = r[i].x;
            lds[(p + 1) * NC + c] = r[i].y;
            lds[(p + 2) * NC + c] = r[i].z;
            lds[(p + 3) * NC + c] = r[i].w;
        }
    }
    __syncthreads();

    // ---- phase 2: ds_read_b128 + transform + contiguous stores ----
    float* ob = out + (size_t)plane * (NPOS * NC) + (size_t)tile * (PPB * NC);
    const float aw = c_aw[a];
    const float ah = c_ah[a];
    const float gy = (float)tile;

    // incremental (p, c) tracking: e0 = 4*(t + BLK*i); step per i: p += 24, c += 8
    int p0 = (4 * t) / NC;
    int c0 = 4 * t - p0 * NC;

    #pragma unroll
    for (int i = 0; i < NITER; ++i) {
        const int v = t + BLK * i;
        if (v < NV) {
            const int e0 = 4 * v;
            const floatx4 f = *reinterpret_cast<const floatx4*>(&lds[e0]);
            float xin[4] = {f.x, f.y, f.z, f.w};
            float res[4];
            int p = p0, c = c0;
            #pragma unroll
            for (int k = 0; k < 4; ++k) {
                const float x = xin[k];
                float rr;
                if (c >= 4) {                    // conf + 80 classes
                    rr = fsig(x);
                } else if (c == 2) {             // box w
                    rr = __expf(x) * aw;
                } else if (c == 3) {             // box h
                    rr = __expf(x) * ah;
                } else {                         // box x / y
                    const float g = (c == 0) ? (float)p : gy;
                    rr = (fsig(x) + g) * STRIDE_F;
                }
                res[k] = rr;
                if (++c == NC) { c = 0; ++p; }
            }
            floatx4 o;
            o.x = res[0]; o.y = res[1]; o.z = res[2]; o.w = res[3];
            *reinterpret_cast<floatx4*>(ob + e0) = o;
        }
        // advance (p0, c0) by 2048 elements = 24*85 + 8
        p0 += 24; c0 += 8;
        if (c0 >= NC) { c0 -= NC; ++p0; }
    }
}

extern "C" void kernel_launch(void* const* d_in, const int* in_sizes, int n_in,
                              void* d_out, int out_size, void* d_ws, size_t ws_size,
                              hipStream_t stream) {
    const float* x = (const float*)d_in[0];
    float* out     = (float*)d_out;
    const int nB     = in_sizes[0] / (NA * NC * NPOS);   // 16
    const int blocks = nB * NA * TPP;                    // 3648
    det_kernel<<<blocks, BLK, 0, stream>>>(x, out);
}